// Round 1
// baseline (1360.227 us; speedup 1.0000x reference)
//
#include <hip/hip_runtime.h>
#include <cstdint>
#include <cstddef>

#define D_MODEL 1024
#define DIN     2048
#define NSTATE  16
#define LSEQ    2048
#define NBATCH  2
#define NROWS   (NBATCH*LSEQ)   // 4096
#define NCOL    (DIN + 128)     // 2176 = Wdt(2048) | WB(16) | WC(16) | pad(96)
#define LOG2E   1.4426950408889634f

typedef float  f32x4  __attribute__((ext_vector_type(4)));
typedef short  bf16x8 __attribute__((ext_vector_type(8)));

__device__ __forceinline__ unsigned short f2bf(float f) {
  union { float f; unsigned u; } c; c.f = f;
  unsigned x = c.u + 0x7fffu + ((c.u >> 16) & 1u);   // RNE
  return (unsigned short)(x >> 16);
}
__device__ __forceinline__ float sigmoidf_(float x) { return 1.f / (1.f + __expf(-x)); }

// ---------------- pos add: X = x + pos_emb ----------------
__global__ __launch_bounds__(256) void pos_kernel(const float* __restrict__ x,
    const float* __restrict__ pos, float* __restrict__ X) {
  int id = blockIdx.x * 256 + threadIdx.x;                  // one float4 each
  const float4 a = *(const float4*)(x + (size_t)id * 4);
  const float4 p = *(const float4*)(pos + (size_t)(id & (LSEQ * D_MODEL / 4 - 1)) * 4);
  float4 o; o.x = a.x + p.x; o.y = a.y + p.y; o.z = a.z + p.z; o.w = a.w + p.w;
  *(float4*)(X + (size_t)id * 4) = o;
}

// ---------------- layernorm (one row per block, D=1024) ----------------
// outB != null -> write bf16; else write fp32 to outF.
__global__ __launch_bounds__(256) void ln_kernel(const float* __restrict__ X,
    const float* __restrict__ w, const float* __restrict__ b,
    unsigned short* __restrict__ outB, float* __restrict__ outF) {
  int row = blockIdx.x, t = threadIdx.x;
  const float4 v = *(const float4*)(X + (size_t)row * D_MODEL + t * 4);
  float s  = v.x + v.y + v.z + v.w;
  float s2 = v.x * v.x + v.y * v.y + v.z * v.z + v.w * v.w;
#pragma unroll
  for (int o = 1; o < 64; o <<= 1) { s += __shfl_xor(s, o, 64); s2 += __shfl_xor(s2, o, 64); }
  __shared__ float ps[8];
  int wv = t >> 6;
  if ((t & 63) == 0) { ps[wv] = s; ps[wv + 4] = s2; }
  __syncthreads();
  s  = ps[0] + ps[1] + ps[2] + ps[3];
  s2 = ps[4] + ps[5] + ps[6] + ps[7];
  float mean = s * (1.f / D_MODEL);
  float var  = s2 * (1.f / D_MODEL) - mean * mean;
  float rs   = rsqrtf(var + 1e-5f);
  const float4 wv4 = *(const float4*)(w + t * 4);
  const float4 bv4 = *(const float4*)(b + t * 4);
  float o0 = (v.x - mean) * rs * wv4.x + bv4.x;
  float o1 = (v.y - mean) * rs * wv4.y + bv4.y;
  float o2 = (v.z - mean) * rs * wv4.z + bv4.z;
  float o3 = (v.w - mean) * rs * wv4.w + bv4.w;
  if (outB) {
    ushort4 o; o.x = f2bf(o0); o.y = f2bf(o1); o.z = f2bf(o2); o.w = f2bf(o3);
    *(ushort4*)(outB + (size_t)row * D_MODEL + t * 4) = o;
  } else {
    float4 o; o.x = o0; o.y = o1; o.z = o2; o.w = o3;
    *(float4*)(outF + (size_t)row * D_MODEL + t * 4) = o;
  }
}

// ---------------- zero (uint4 granularity, exact grid) ----------------
__global__ __launch_bounds__(256) void zero_kernel(uint4* __restrict__ p) {
  int id = blockIdx.x * 256 + threadIdx.x;
  uint4 z; z.x = z.y = z.z = z.w = 0u;
  p[id] = z;
}

// ---------------- transpose + fp32->bf16: out[n][k] = in[k][n] ----------------
__global__ __launch_bounds__(256) void tcvt_kernel(const float* __restrict__ in,
    unsigned short* __restrict__ out, int K_, int N_) {
  __shared__ float tile[64][68];                       // pad 68 to break conflicts
  int n0 = blockIdx.x * 64, k0 = blockIdx.y * 64;
  int t = threadIdx.x;
  int r = t >> 4, cc = (t & 15) * 4;
#pragma unroll
  for (int j = 0; j < 4; j++) {
    const float4 v = *(const float4*)(in + (size_t)(k0 + r + j * 16) * N_ + n0 + cc);
    tile[r + j * 16][cc + 0] = v.x; tile[r + j * 16][cc + 1] = v.y;
    tile[r + j * 16][cc + 2] = v.z; tile[r + j * 16][cc + 3] = v.w;
  }
  __syncthreads();
  int nr = t >> 2, kc = (t & 3) * 16;
  unsigned u[8];
#pragma unroll
  for (int i = 0; i < 8; i++) {
    unsigned lo = f2bf(tile[kc + 2 * i][nr]);
    unsigned hi = f2bf(tile[kc + 2 * i + 1][nr]);
    u[i] = lo | (hi << 16);
  }
  uint4* dst = (uint4*)(out + (size_t)(n0 + nr) * K_ + k0 + kc);
  uint4 w0; w0.x = u[0]; w0.y = u[1]; w0.z = u[2]; w0.w = u[3];
  uint4 w1; w1.x = u[4]; w1.y = u[5]; w1.z = u[6]; w1.w = u[7];
  dst[0] = w0; dst[1] = w1;
}

// ---------------- fill WB^T/WC^T rows (2048..2079) of WdtBC^T ----------------
__global__ __launch_bounds__(256) void bcfill_kernel(const float* __restrict__ WB,
    const float* __restrict__ WC, unsigned short* __restrict__ out) {
  int id = blockIdx.x * 256 + threadIdx.x;             // 32*2048
  int k = id & (DIN - 1);
  int n2 = id >> 11;
  float v = (n2 < NSTATE) ? WB[(size_t)k * NSTATE + n2]
                          : WC[(size_t)k * NSTATE + (n2 - NSTATE)];
  out[(size_t)(DIN + n2) * DIN + k] = f2bf(v);
}

__global__ __launch_bounds__(256) void biasfill_kernel(const float* __restrict__ b_dt,
    float* __restrict__ out) {
  int i = blockIdx.x * 256 + threadIdx.x;
  if (i < NCOL) out[i] = (i < DIN) ? b_dt[i] : 0.f;
}

// ---------------- bf16 MFMA GEMM: out = A[M][K] @ Bt[N][K]^T + bias (+res) ----
// 128x128 tile, BK=32, 4 waves x (4x4) 16x16x32 fragments, reg-staged LDS.
template <bool HAS_RES, bool WRITE_BF>
__global__ __launch_bounds__(256) void gemm_kernel(
    const unsigned short* __restrict__ A, const unsigned short* __restrict__ Bt,
    const float* __restrict__ bias, const float* res,
    float* outF, unsigned short* __restrict__ outB,
    int M, int N, int K) {
  __shared__ unsigned short sA[128 * 32];
  __shared__ unsigned short sB[128 * 32];
  const int t = threadIdx.x;
  const int lane = t & 63, wave = t >> 6;
  const int wr = wave >> 1, wc = wave & 1;
  const int m0 = blockIdx.y * 128, n0 = blockIdx.x * 128;
  const int ar = t >> 2, ac = (t & 3) * 8;             // staging: 16B per thread/chunk

  f32x4 acc[4][4];
#pragma unroll
  for (int m = 0; m < 4; m++)
#pragma unroll
    for (int n = 0; n < 4; n++) acc[m][n] = (f32x4)0.f;

  const int lr = lane & 15, lk = (lane >> 4) * 8;

  for (int k0 = 0; k0 < K; k0 += 32) {
    const uint4 va0 = *(const uint4*)(A + (size_t)(m0 + ar) * K + k0 + ac);
    const uint4 va1 = *(const uint4*)(A + (size_t)(m0 + 64 + ar) * K + k0 + ac);
    const uint4 vb0 = *(const uint4*)(Bt + (size_t)(n0 + ar) * K + k0 + ac);
    const uint4 vb1 = *(const uint4*)(Bt + (size_t)(n0 + 64 + ar) * K + k0 + ac);
    __syncthreads();                                    // previous iter's reads done
    ((uint4*)sA)[t] = va0; ((uint4*)sA)[256 + t] = va1;
    ((uint4*)sB)[t] = vb0; ((uint4*)sB)[256 + t] = vb1;
    __syncthreads();
    bf16x8 af[4], bg[4];
#pragma unroll
    for (int m = 0; m < 4; m++)
      af[m] = *(const bf16x8*)(sA + (wr * 64 + m * 16 + lr) * 32 + lk);
#pragma unroll
    for (int n = 0; n < 4; n++)
      bg[n] = *(const bf16x8*)(sB + (wc * 64 + n * 16 + lr) * 32 + lk);
#pragma unroll
    for (int m = 0; m < 4; m++)
#pragma unroll
      for (int n = 0; n < 4; n++)
        acc[m][n] = __builtin_amdgcn_mfma_f32_16x16x32_bf16(af[m], bg[n], acc[m][n], 0, 0, 0);
  }

  const int lq = lane >> 4;
#pragma unroll
  for (int m = 0; m < 4; m++) {
    int row = m0 + wr * 64 + m * 16 + lq * 4;
#pragma unroll
    for (int n = 0; n < 4; n++) {
      int col = n0 + wc * 64 + n * 16 + lr;
      float bv = bias[col];
#pragma unroll
      for (int j = 0; j < 4; j++) {
        size_t idx = (size_t)(row + j) * N + col;
        float v = acc[m][n][j] + bv;
        if (HAS_RES) v += res[idx];
        outF[idx] = v;
        if (WRITE_BF) outB[idx] = f2bf(v);
      }
    }
  }
}

// ---------------- selective scan ----------------
// block = 256 threads = 16 channels x 16 states; grid (DIN/16, B).
// DT layout: [B*L][NCOL] with dt_pre cols [0,2048), Bm [2048,2064), Cm [2064,2080).
__global__ __launch_bounds__(256) void scan_kernel(const float* __restrict__ DT,
    const float* __restrict__ H, const float* __restrict__ A_log,
    float* __restrict__ Y) {
  const int b = blockIdx.y;
  const int d0 = blockIdx.x * 16;
  const int tid = threadIdx.x;
  const int n = tid & 15, dl = tid >> 4;
  __shared__ float sdt[64][16], sdx[64][16], sBv[64][16], sCv[64][16];
  const float a2 = -__expf(A_log[(size_t)(d0 + dl) * NSTATE + n]) * LOG2E;
  float h = 0.f;
  const int tr = tid >> 2, tc = (tid & 3) * 4;
  const int base = b * LSEQ;
  for (int c = 0; c < LSEQ / 64; ++c) {
    const int t0 = c * 64;
    const size_t rowb = (size_t)(base + t0 + tr);
    const float4 vdt = *(const float4*)(DT + rowb * NCOL + d0 + tc);
    const float4 vx  = *(const float4*)(H + rowb * DIN + d0 + tc);
    const float4 vB  = *(const float4*)(DT + rowb * NCOL + DIN + tc);
    const float4 vC  = *(const float4*)(DT + rowb * NCOL + DIN + 16 + tc);
    __syncthreads();                                    // prev chunk fully consumed
    {                                                   // softplus(x)=max(x,0)+log1p(exp(-|x|))
      float d0v = fmaxf(vdt.x, 0.f) + log1pf(__expf(-fabsf(vdt.x)));
      float d1v = fmaxf(vdt.y, 0.f) + log1pf(__expf(-fabsf(vdt.y)));
      float d2v = fmaxf(vdt.z, 0.f) + log1pf(__expf(-fabsf(vdt.z)));
      float d3v = fmaxf(vdt.w, 0.f) + log1pf(__expf(-fabsf(vdt.w)));
      sdt[tr][tc + 0] = d0v; sdx[tr][tc + 0] = d0v * vx.x;
      sdt[tr][tc + 1] = d1v; sdx[tr][tc + 1] = d1v * vx.y;
      sdt[tr][tc + 2] = d2v; sdx[tr][tc + 2] = d2v * vx.z;
      sdt[tr][tc + 3] = d3v; sdx[tr][tc + 3] = d3v * vx.w;
      sBv[tr][tc + 0] = vB.x; sBv[tr][tc + 1] = vB.y; sBv[tr][tc + 2] = vB.z; sBv[tr][tc + 3] = vB.w;
      sCv[tr][tc + 0] = vC.x; sCv[tr][tc + 1] = vC.y; sCv[tr][tc + 2] = vC.z; sCv[tr][tc + 3] = vC.w;
    }
    __syncthreads();
#pragma unroll 4
    for (int tt = 0; tt < 64; ++tt) {
      float dA = exp2f(sdt[tt][dl] * a2);
      h = fmaf(h, dA, sdx[tt][dl] * sBv[tt][n]);
      float py = h * sCv[tt][n];
      py += __shfl_xor(py, 1, 16);
      py += __shfl_xor(py, 2, 16);
      py += __shfl_xor(py, 4, 16);
      py += __shfl_xor(py, 8, 16);
      if (n == 0) Y[(size_t)(base + t0 + tt) * DIN + d0 + dl] = py;
    }
  }
}

// ---------------- conv + silu + gating: G = bf16((Y + H*Dsk)*sigmoid(silu(conv(H)))) --
__global__ __launch_bounds__(256) void gate_kernel(const float* __restrict__ H,
    const float* __restrict__ Y, const float* __restrict__ cw,
    const float* __restrict__ cb, const float* __restrict__ dsk,
    unsigned short* __restrict__ G) {
  int id = blockIdx.x * 256 + threadIdx.x;              // one float4 of DIN
  int d4 = id & (DIN / 4 - 1);
  int bt = id >> 9;
  int t = bt & (LSEQ - 1);
  const float4 h  = *(const float4*)(H + (size_t)bt * DIN + d4 * 4);
  const float4 w3 = *(const float4*)(cw + 3 * DIN + d4 * 4);
  const float4 cbv = *(const float4*)(cb + d4 * 4);
  float a0 = cbv.x + h.x * w3.x, a1 = cbv.y + h.y * w3.y;
  float a2 = cbv.z + h.z * w3.z, a3 = cbv.w + h.w * w3.w;
#pragma unroll
  for (int k = 0; k < 3; k++) {
    int ts = t - 3 + k;
    if (ts >= 0) {
      const float4 hv = *(const float4*)(H + (size_t)(bt - 3 + k) * DIN + d4 * 4);
      const float4 w  = *(const float4*)(cw + k * DIN + d4 * 4);
      a0 += hv.x * w.x; a1 += hv.y * w.y; a2 += hv.z * w.z; a3 += hv.w * w.w;
    }
  }
  const float4 y  = *(const float4*)(Y + (size_t)bt * DIN + d4 * 4);
  const float4 ds = *(const float4*)(dsk + d4 * 4);
  float s0 = a0 * sigmoidf_(a0), s1 = a1 * sigmoidf_(a1);
  float s2 = a2 * sigmoidf_(a2), s3 = a3 * sigmoidf_(a3);
  ushort4 o;
  o.x = f2bf((y.x + h.x * ds.x) * sigmoidf_(s0));
  o.y = f2bf((y.y + h.y * ds.y) * sigmoidf_(s1));
  o.z = f2bf((y.z + h.z * ds.z) * sigmoidf_(s2));
  o.w = f2bf((y.w + h.w * ds.w) * sigmoidf_(s3));
  *(ushort4*)(G + (size_t)bt * DIN + d4 * 4) = o;
}

// ---------------- launch ----------------
extern "C" void kernel_launch(void* const* d_in, const int* in_sizes, int n_in,
                              void* d_out, int out_size, void* d_ws, size_t ws_size,
                              hipStream_t stream) {
  const float* x_in   = (const float*)d_in[0];
  const float* pos    = (const float*)d_in[1];
  const float* norm_w = (const float*)d_in[2];
  const float* norm_b = (const float*)d_in[3];
  const float* Win    = (const float*)d_in[4];
  const float* b_in   = (const float*)d_in[5];
  const float* A_log  = (const float*)d_in[6];
  const float* Wdt    = (const float*)d_in[7];
  const float* b_dt   = (const float*)d_in[8];
  const float* WB     = (const float*)d_in[9];
  const float* WC     = (const float*)d_in[10];
  const float* Dsk    = (const float*)d_in[11];
  const float* conv_w = (const float*)d_in[12];
  const float* conv_b = (const float*)d_in[13];
  const float* Wout   = (const float*)d_in[14];
  const float* b_out  = (const float*)d_in[15];
  const float* fnw    = (const float*)d_in[16];
  const float* fnb    = (const float*)d_in[17];

  uint8_t* ws = (uint8_t*)d_ws;
  // workspace layout (bytes)
  constexpr size_t OFF_X      = 0;                       // [4096][1024] f32   16 MB
  constexpr size_t OFF_H      = 16777216;                // [4096][2048] f32   32 MB
  constexpr size_t OFF_HBF    = 50331648;                // [4096][2048] bf16  16 MB
  constexpr size_t OFF_DTBC   = 67108864;                // [4096][2176] f32   34 MB
  constexpr size_t OFF_Y      = 102760448;               // [4096][2048] f32   32 MB
  constexpr size_t OFF_XNG    = 136314880;               // Xn bf16 (8MB) / G bf16 (16MB), disjoint lifetimes
  constexpr size_t OFF_WINT   = 153092096;               // [2048][1024] bf16   4 MB
  constexpr size_t OFF_WDTBCT = 157286400;               // [2176][2048] bf16 ~8.5 MB
  constexpr size_t OFF_WOUTT  = 166199296;               // [1024][2048] bf16   4 MB
  constexpr size_t OFF_BIAS2  = 170393600;               // [2176] f32
  constexpr size_t WS_NEEDED  = 170402304;
  if (ws_size < WS_NEEDED) return;                       // cannot run

  float* X            = (float*)(ws + OFF_X);
  float* Hb           = (float*)(ws + OFF_H);
  unsigned short* Hbf = (unsigned short*)(ws + OFF_HBF);
  float* DTBC         = (float*)(ws + OFF_DTBC);
  float* Yb           = (float*)(ws + OFF_Y);
  unsigned short* Xn  = (unsigned short*)(ws + OFF_XNG);
  unsigned short* Gb  = (unsigned short*)(ws + OFF_XNG);
  unsigned short* WinT   = (unsigned short*)(ws + OFF_WINT);
  unsigned short* WdtBCT = (unsigned short*)(ws + OFF_WDTBCT);
  unsigned short* WoutT  = (unsigned short*)(ws + OFF_WOUTT);
  float* bias2        = (float*)(ws + OFF_BIAS2);

  pos_kernel<<<4096, 256, 0, stream>>>(x_in, pos, X);

  for (int i = 0; i < 2; i++) {
    // ---- weight prep (bf16, transposed to [N][K]) ----
    tcvt_kernel<<<dim3(2048 / 64, 1024 / 64), 256, 0, stream>>>(
        Win + (size_t)i * D_MODEL * DIN, WinT, 1024, 2048);
    zero_kernel<<<(2176 * 2048 * 2 / 16) / 256, 256, 0, stream>>>((uint4*)WdtBCT);
    tcvt_kernel<<<dim3(2048 / 64, 2048 / 64), 256, 0, stream>>>(
        Wdt + (size_t)i * DIN * DIN, WdtBCT, 2048, 2048);
    bcfill_kernel<<<(32 * 2048) / 256, 256, 0, stream>>>(
        WB + (size_t)i * DIN * NSTATE, WC + (size_t)i * DIN * NSTATE, WdtBCT);
    biasfill_kernel<<<9, 256, 0, stream>>>(b_dt + (size_t)i * DIN, bias2);
    tcvt_kernel<<<dim3(1024 / 64, 2048 / 64), 256, 0, stream>>>(
        Wout + (size_t)i * DIN * D_MODEL, WoutT, 2048, 1024);

    // ---- layer compute ----
    ln_kernel<<<4096, 256, 0, stream>>>(X, norm_w + i * D_MODEL, norm_b + i * D_MODEL,
                                        Xn, nullptr);
    gemm_kernel<false, true><<<dim3(2048 / 128, 4096 / 128), 256, 0, stream>>>(
        Xn, WinT, b_in + (size_t)i * DIN, nullptr, Hb, Hbf, NROWS, DIN, D_MODEL);
    gemm_kernel<false, false><<<dim3(NCOL / 128, 4096 / 128), 256, 0, stream>>>(
        Hbf, WdtBCT, bias2, nullptr, DTBC, nullptr, NROWS, NCOL, DIN);
    scan_kernel<<<dim3(DIN / 16, NBATCH), 256, 0, stream>>>(
        DTBC, Hb, A_log + (size_t)i * DIN * NSTATE, Yb);
    gate_kernel<<<(NBATCH * LSEQ * DIN / 4) / 256, 256, 0, stream>>>(
        Hb, Yb, conv_w + (size_t)i * 4 * DIN, conv_b + (size_t)i * DIN,
        Dsk + (size_t)i * DIN, Gb);
    gemm_kernel<true, false><<<dim3(1024 / 128, 4096 / 128), 256, 0, stream>>>(
        Gb, WoutT, b_out + (size_t)i * D_MODEL, X, X, nullptr, NROWS, D_MODEL, DIN);
  }

  ln_kernel<<<4096, 256, 0, stream>>>(X, fnw, fnb, nullptr, (float*)d_out);
}

// Round 3
// 750.688 us; speedup vs baseline: 1.8120x; 1.8120x over previous
//
#include <hip/hip_runtime.h>
#include <cstdint>
#include <cstddef>

#define D_MODEL 1024
#define DIN     2048
#define NSTATE  16
#define LSEQ    2048
#define NBATCH  2
#define NROWS   (NBATCH*LSEQ)   // 4096
#define NCOL    (DIN + 128)     // 2176 = sp(2048) | B(16) | C(16) | pad(96)
#define CCH     32              // scan chunks
#define TC      (LSEQ/CCH)      // 64 steps per chunk
#define LOG2E   1.4426950408889634f

typedef float  f32x4  __attribute__((ext_vector_type(4)));
typedef short  bf16x8 __attribute__((ext_vector_type(8)));

__device__ __forceinline__ unsigned short f2bf(float f) {
  union { float f; unsigned u; } c; c.f = f;
  unsigned x = c.u + 0x7fffu + ((c.u >> 16) & 1u);   // RNE
  return (unsigned short)(x >> 16);
}
__device__ __forceinline__ float sigmoidf_(float x) { return 1.f / (1.f + __expf(-x)); }
__device__ __forceinline__ float softplusf_(float x) {
  return fmaxf(x, 0.f) + log1pf(__expf(-fabsf(x)));
}

// async global->LDS, 16B per lane; lds dest = wave-uniform base + lane*16
__device__ __forceinline__ void gll16(const void* g, void* l) {
  __builtin_amdgcn_global_load_lds(
      (const __attribute__((address_space(1))) void*)g,
      (__attribute__((address_space(3))) void*)l, 16, 0, 0);
}

// ---------------- pos add: X = x + pos_emb ----------------
__global__ __launch_bounds__(256) void pos_kernel(const float* __restrict__ x,
    const float* __restrict__ pos, float* __restrict__ X) {
  int id = blockIdx.x * 256 + threadIdx.x;                  // one float4 each
  const float4 a = *(const float4*)(x + (size_t)id * 4);
  const float4 p = *(const float4*)(pos + (size_t)(id & (LSEQ * D_MODEL / 4 - 1)) * 4);
  float4 o; o.x = a.x + p.x; o.y = a.y + p.y; o.z = a.z + p.z; o.w = a.w + p.w;
  *(float4*)(X + (size_t)id * 4) = o;
}

// ---------------- layernorm (one row per block, D=1024) ----------------
__global__ __launch_bounds__(256) void ln_kernel(const float* __restrict__ X,
    const float* __restrict__ w, const float* __restrict__ b,
    unsigned short* __restrict__ outB, float* __restrict__ outF) {
  int row = blockIdx.x, t = threadIdx.x;
  const float4 v = *(const float4*)(X + (size_t)row * D_MODEL + t * 4);
  float s  = v.x + v.y + v.z + v.w;
  float s2 = v.x * v.x + v.y * v.y + v.z * v.z + v.w * v.w;
#pragma unroll
  for (int o = 1; o < 64; o <<= 1) { s += __shfl_xor(s, o, 64); s2 += __shfl_xor(s2, o, 64); }
  __shared__ float ps[8];
  int wv = t >> 6;
  if ((t & 63) == 0) { ps[wv] = s; ps[wv + 4] = s2; }
  __syncthreads();
  s  = ps[0] + ps[1] + ps[2] + ps[3];
  s2 = ps[4] + ps[5] + ps[6] + ps[7];
  float mean = s * (1.f / D_MODEL);
  float var  = s2 * (1.f / D_MODEL) - mean * mean;
  float rs   = rsqrtf(var + 1e-5f);
  const float4 wv4 = *(const float4*)(w + t * 4);
  const float4 bv4 = *(const float4*)(b + t * 4);
  float o0 = (v.x - mean) * rs * wv4.x + bv4.x;
  float o1 = (v.y - mean) * rs * wv4.y + bv4.y;
  float o2 = (v.z - mean) * rs * wv4.z + bv4.z;
  float o3 = (v.w - mean) * rs * wv4.w + bv4.w;
  if (outB) {
    ushort4 o; o.x = f2bf(o0); o.y = f2bf(o1); o.z = f2bf(o2); o.w = f2bf(o3);
    *(ushort4*)(outB + (size_t)row * D_MODEL + t * 4) = o;
  } else {
    float4 o; o.x = o0; o.y = o1; o.z = o2; o.w = o3;
    *(float4*)(outF + (size_t)row * D_MODEL + t * 4) = o;
  }
}

// ---------------- zero (uint4 granularity, exact grid) ----------------
__global__ __launch_bounds__(256) void zero_kernel(uint4* __restrict__ p) {
  int id = blockIdx.x * 256 + threadIdx.x;
  uint4 z; z.x = z.y = z.z = z.w = 0u;
  p[id] = z;
}

// ---------------- transpose + fp32->bf16: out[n][k] = in[k][n] ----------------
__global__ __launch_bounds__(256) void tcvt_kernel(const float* __restrict__ in,
    unsigned short* __restrict__ out, int K_, int N_) {
  __shared__ float tile[64][68];
  int n0 = blockIdx.x * 64, k0 = blockIdx.y * 64;
  int t = threadIdx.x;
  int r = t >> 4, cc = (t & 15) * 4;
#pragma unroll
  for (int j = 0; j < 4; j++) {
    const float4 v = *(const float4*)(in + (size_t)(k0 + r + j * 16) * N_ + n0 + cc);
    tile[r + j * 16][cc + 0] = v.x; tile[r + j * 16][cc + 1] = v.y;
    tile[r + j * 16][cc + 2] = v.z; tile[r + j * 16][cc + 3] = v.w;
  }
  __syncthreads();
  int nr = t >> 2, kc = (t & 3) * 16;
  unsigned u[8];
#pragma unroll
  for (int i = 0; i < 8; i++) {
    unsigned lo = f2bf(tile[kc + 2 * i][nr]);
    unsigned hi = f2bf(tile[kc + 2 * i + 1][nr]);
    u[i] = lo | (hi << 16);
  }
  uint4* dst = (uint4*)(out + (size_t)(n0 + nr) * K_ + k0 + kc);
  uint4 w0; w0.x = u[0]; w0.y = u[1]; w0.z = u[2]; w0.w = u[3];
  uint4 w1; w1.x = u[4]; w1.y = u[5]; w1.z = u[6]; w1.w = u[7];
  dst[0] = w0; dst[1] = w1;
}

// ---------------- fill WB^T/WC^T rows (2048..2079) of WdtBC^T ----------------
__global__ __launch_bounds__(256) void bcfill_kernel(const float* __restrict__ WB,
    const float* __restrict__ WC, unsigned short* __restrict__ out) {
  int id = blockIdx.x * 256 + threadIdx.x;             // 32*2048
  int k = id & (DIN - 1);
  int n2 = id >> 11;
  float v = (n2 < NSTATE) ? WB[(size_t)k * NSTATE + n2]
                          : WC[(size_t)k * NSTATE + (n2 - NSTATE)];
  out[(size_t)(DIN + n2) * DIN + k] = f2bf(v);
}

__global__ __launch_bounds__(256) void biasfill_kernel(const float* __restrict__ b_dt,
    float* __restrict__ out) {
  int i = blockIdx.x * 256 + threadIdx.x;
  if (i < NCOL) out[i] = (i < DIN) ? b_dt[i] : 0.f;
}

// ---------------- bf16 MFMA GEMM: out = A[M][K] @ Bt[N][K]^T + bias (+res) ----
// 128x128 tile, BK=32, 4 waves x (4x4) 16x16x32 frags, global_load_lds staging (m97).
template <bool HAS_RES, bool WRITE_BF>
__global__ __launch_bounds__(256) void gemm_kernel(
    const unsigned short* __restrict__ A, const unsigned short* __restrict__ Bt,
    const float* __restrict__ bias, const float* res,
    float* outF, unsigned short* __restrict__ outB,
    int M, int N, int K, int spCols) {
  __shared__ unsigned short sA[128 * 32];
  __shared__ unsigned short sB[128 * 32];
  const int t = threadIdx.x;
  const int lane = t & 63, wave = t >> 6;
  const int wr = wave >> 1, wc = wave & 1;
  const int m0 = blockIdx.y * 128, n0 = blockIdx.x * 128;
  const int ar = t >> 2, ac = (t & 3) * 8;             // staging: 16B/lane, linear in LDS
  const int wseg = wave * 16 * 32;                     // wave-uniform LDS base (elements)

  f32x4 acc[4][4];
#pragma unroll
  for (int m = 0; m < 4; m++)
#pragma unroll
    for (int n = 0; n < 4; n++) acc[m][n] = (f32x4)0.f;

  const int lr = lane & 15, lk = (lane >> 4) * 8;

  for (int k0 = 0; k0 < K; k0 += 32) {
    __syncthreads();                                    // prev tile fully consumed
    gll16(A  + (size_t)(m0 + ar) * K + k0 + ac,      sA + wseg);
    gll16(A  + (size_t)(m0 + 64 + ar) * K + k0 + ac, sA + 64 * 32 + wseg);
    gll16(Bt + (size_t)(n0 + ar) * K + k0 + ac,      sB + wseg);
    gll16(Bt + (size_t)(n0 + 64 + ar) * K + k0 + ac, sB + 64 * 32 + wseg);
    __syncthreads();                                    // drains vmcnt -> tile ready
    bf16x8 af[4], bg[4];
#pragma unroll
    for (int m = 0; m < 4; m++)
      af[m] = *(const bf16x8*)(sA + (wr * 64 + m * 16 + lr) * 32 + lk);
#pragma unroll
    for (int n = 0; n < 4; n++)
      bg[n] = *(const bf16x8*)(sB + (wc * 64 + n * 16 + lr) * 32 + lk);
#pragma unroll
    for (int m = 0; m < 4; m++)
#pragma unroll
      for (int n = 0; n < 4; n++)
        acc[m][n] = __builtin_amdgcn_mfma_f32_16x16x32_bf16(af[m], bg[n], acc[m][n], 0, 0, 0);
  }

  const int lq = lane >> 4;
#pragma unroll
  for (int m = 0; m < 4; m++) {
    int row = m0 + wr * 64 + m * 16 + lq * 4;
#pragma unroll
    for (int n = 0; n < 4; n++) {
      int col = n0 + wc * 64 + n * 16 + lr;
      float bv = bias[col];
      bool sp = col < spCols;
#pragma unroll
      for (int j = 0; j < 4; j++) {
        size_t idx = (size_t)(row + j) * N + col;
        float v = acc[m][n][j] + bv;
        if (HAS_RES) v += res[idx];
        if (sp) v = softplusf_(v);
        outF[idx] = v;
        if (WRITE_BF) outB[idx] = f2bf(v);
      }
    }
  }
}

// ---------------- chunked selective scan ----------------
// Thread owns one channel d and all 16 states in registers. grid (DIN/256, B, CCH).
// DTBC: [B*L][NCOL], cols [0,2048)=softplus(dt), [2048,2064)=B, [2064,2080)=C.
// scan1: local scan from h=0 over TC steps -> Hc[c][chain][16], Pc[c][chain][16].
__global__ __launch_bounds__(256) void scan1_kernel(const float* __restrict__ DTBC,
    const float* __restrict__ H, const float* __restrict__ A_log,
    float* __restrict__ Hc, float* __restrict__ Pc) {
  const int d = blockIdx.x * 256 + threadIdx.x;
  const int b = blockIdx.y, c = blockIdx.z;
  float a2[16], h[16];
#pragma unroll
  for (int n = 0; n < 16; n++) {
    a2[n] = -__expf(A_log[(size_t)d * NSTATE + n]) * LOG2E;
    h[n] = 0.f;
  }
  __shared__ float sBC[TC][32];                        // B | C per step
  {
    int idx = threadIdx.x * 8;                          // 2048 floats total
    int tt = idx >> 5, col = idx & 31;
    const size_t row = (size_t)(b * LSEQ + c * TC + tt);
    *(float4*)(&sBC[tt][col])     = *(const float4*)(DTBC + row * NCOL + DIN + col);
    *(float4*)(&sBC[tt][col + 4]) = *(const float4*)(DTBC + row * NCOL + DIN + col + 4);
  }
  __syncthreads();
  float S = 0.f;
  const size_t base = (size_t)(b * LSEQ + c * TC);
  for (int tt = 0; tt < TC; ++tt) {
    float sp = DTBC[(base + tt) * NCOL + d];
    float x  = H[(base + tt) * DIN + d];
    S += sp;
    float sx = sp * x;
#pragma unroll
    for (int n = 0; n < 16; n++)
      h[n] = fmaf(h[n], exp2f(sp * a2[n]), sx * sBC[tt][n]);
  }
  const size_t chain = ((size_t)c * (NBATCH * DIN) + (size_t)b * DIN + d) * 16;
#pragma unroll
  for (int n = 0; n < 16; n++) {
    Hc[chain + n] = h[n];
    Pc[chain + n] = exp2f(S * a2[n]);
  }
}

// combine: per (chain,n), sequential over chunks; in-place Hc -> Hinit.
__global__ __launch_bounds__(256) void scomb_kernel(float* __restrict__ Hc,
    const float* __restrict__ Pc) {
  const size_t id = (size_t)blockIdx.x * 256 + threadIdx.x;   // 65536 threads
  const size_t stride = (size_t)NBATCH * DIN * NSTATE;
  float h = 0.f;
  for (int c = 0; c < CCH; c++) {
    size_t o = (size_t)c * stride + id;
    float hl = Hc[o], p = Pc[o];
    Hc[o] = h;                                          // init state for chunk c
    h = fmaf(p, h, hl);
  }
}

// scan2: re-run local scan from Hinit, emit y = sum_n C*h.
__global__ __launch_bounds__(256) void scan2_kernel(const float* __restrict__ DTBC,
    const float* __restrict__ H, const float* __restrict__ A_log,
    const float* __restrict__ Hinit, float* __restrict__ Y) {
  const int d = blockIdx.x * 256 + threadIdx.x;
  const int b = blockIdx.y, c = blockIdx.z;
  const size_t chain = ((size_t)c * (NBATCH * DIN) + (size_t)b * DIN + d) * 16;
  float a2[16], h[16];
#pragma unroll
  for (int n = 0; n < 16; n++) {
    a2[n] = -__expf(A_log[(size_t)d * NSTATE + n]) * LOG2E;
    h[n] = Hinit[chain + n];
  }
  __shared__ float sBC[TC][32];
  {
    int idx = threadIdx.x * 8;
    int tt = idx >> 5, col = idx & 31;
    const size_t row = (size_t)(b * LSEQ + c * TC + tt);
    *(float4*)(&sBC[tt][col])     = *(const float4*)(DTBC + row * NCOL + DIN + col);
    *(float4*)(&sBC[tt][col + 4]) = *(const float4*)(DTBC + row * NCOL + DIN + col + 4);
  }
  __syncthreads();
  const size_t base = (size_t)(b * LSEQ + c * TC);
  for (int tt = 0; tt < TC; ++tt) {
    float sp = DTBC[(base + tt) * NCOL + d];
    float x  = H[(base + tt) * DIN + d];
    float sx = sp * x;
    float y0 = 0.f, y1 = 0.f, y2 = 0.f, y3 = 0.f;
#pragma unroll
    for (int n = 0; n < 16; n += 4) {
      h[n]     = fmaf(h[n],     exp2f(sp * a2[n]),     sx * sBC[tt][n]);
      h[n + 1] = fmaf(h[n + 1], exp2f(sp * a2[n + 1]), sx * sBC[tt][n + 1]);
      h[n + 2] = fmaf(h[n + 2], exp2f(sp * a2[n + 2]), sx * sBC[tt][n + 2]);
      h[n + 3] = fmaf(h[n + 3], exp2f(sp * a2[n + 3]), sx * sBC[tt][n + 3]);
      y0 = fmaf(h[n],     sBC[tt][16 + n],     y0);
      y1 = fmaf(h[n + 1], sBC[tt][16 + n + 1], y1);
      y2 = fmaf(h[n + 2], sBC[tt][16 + n + 2], y2);
      y3 = fmaf(h[n + 3], sBC[tt][16 + n + 3], y3);
    }
    Y[(base + tt) * DIN + d] = (y0 + y1) + (y2 + y3);
  }
}

// ---------------- conv + silu + gating ----------------
__global__ __launch_bounds__(256) void gate_kernel(const float* __restrict__ H,
    const float* __restrict__ Y, const float* __restrict__ cw,
    const float* __restrict__ cb, const float* __restrict__ dsk,
    unsigned short* __restrict__ G) {
  int id = blockIdx.x * 256 + threadIdx.x;
  int d4 = id & (DIN / 4 - 1);
  int bt = id >> 9;
  int t = bt & (LSEQ - 1);
  const float4 h  = *(const float4*)(H + (size_t)bt * DIN + d4 * 4);
  const float4 w3 = *(const float4*)(cw + 3 * DIN + d4 * 4);
  const float4 cbv = *(const float4*)(cb + d4 * 4);
  float a0 = cbv.x + h.x * w3.x, a1 = cbv.y + h.y * w3.y;
  float a2 = cbv.z + h.z * w3.z, a3 = cbv.w + h.w * w3.w;
#pragma unroll
  for (int k = 0; k < 3; k++) {
    int ts = t - 3 + k;
    if (ts >= 0) {
      const float4 hv = *(const float4*)(H + (size_t)(bt - 3 + k) * DIN + d4 * 4);
      const float4 w  = *(const float4*)(cw + k * DIN + d4 * 4);
      a0 += hv.x * w.x; a1 += hv.y * w.y; a2 += hv.z * w.z; a3 += hv.w * w.w;
    }
  }
  const float4 y  = *(const float4*)(Y + (size_t)bt * DIN + d4 * 4);
  const float4 ds = *(const float4*)(dsk + d4 * 4);
  float s0 = a0 * sigmoidf_(a0), s1 = a1 * sigmoidf_(a1);
  float s2 = a2 * sigmoidf_(a2), s3 = a3 * sigmoidf_(a3);
  ushort4 o;
  o.x = f2bf((y.x + h.x * ds.x) * sigmoidf_(s0));
  o.y = f2bf((y.y + h.y * ds.y) * sigmoidf_(s1));
  o.z = f2bf((y.z + h.z * ds.z) * sigmoidf_(s2));
  o.w = f2bf((y.w + h.w * ds.w) * sigmoidf_(s3));
  *(ushort4*)(G + (size_t)bt * DIN + d4 * 4) = o;
}

// ---------------- launch ----------------
extern "C" void kernel_launch(void* const* d_in, const int* in_sizes, int n_in,
                              void* d_out, int out_size, void* d_ws, size_t ws_size,
                              hipStream_t stream) {
  const float* x_in   = (const float*)d_in[0];
  const float* pos    = (const float*)d_in[1];
  const float* norm_w = (const float*)d_in[2];
  const float* norm_b = (const float*)d_in[3];
  const float* Win    = (const float*)d_in[4];
  const float* b_in   = (const float*)d_in[5];
  const float* A_log  = (const float*)d_in[6];
  const float* Wdt    = (const float*)d_in[7];
  const float* b_dt   = (const float*)d_in[8];
  const float* WB     = (const float*)d_in[9];
  const float* WC     = (const float*)d_in[10];
  const float* Dsk    = (const float*)d_in[11];
  const float* conv_w = (const float*)d_in[12];
  const float* conv_b = (const float*)d_in[13];
  const float* Wout   = (const float*)d_in[14];
  const float* b_out  = (const float*)d_in[15];
  const float* fnw    = (const float*)d_in[16];
  const float* fnb    = (const float*)d_in[17];

  uint8_t* ws = (uint8_t*)d_ws;
  constexpr size_t OFF_X      = 0;                       // [4096][1024] f32   16 MB
  constexpr size_t OFF_H      = 16777216;                // [4096][2048] f32   32 MB
  constexpr size_t OFF_HBF    = 50331648;                // [4096][2048] bf16  16 MB
  constexpr size_t OFF_DTBC   = 67108864;                // [4096][2176] f32   34 MB
  constexpr size_t OFF_Y      = 102760448;               // [4096][2048] f32   32 MB
  constexpr size_t OFF_XNG    = 136314880;               // Xn bf16 / {Hc,Pc} / G bf16 (disjoint lifetimes), 16 MB
  constexpr size_t OFF_WINT   = 153092096;               // [2048][1024] bf16   4 MB
  constexpr size_t OFF_WDTBCT = 157286400;               // [2176][2048] bf16 ~8.5 MB
  constexpr size_t OFF_WOUTT  = 166199296;               // [1024][2048] bf16   4 MB
  constexpr size_t OFF_BIAS2  = 170393600;               // [2176] f32
  constexpr size_t WS_NEEDED  = 170402304;
  if (ws_size < WS_NEEDED) return;

  float* X            = (float*)(ws + OFF_X);
  float* Hb           = (float*)(ws + OFF_H);
  unsigned short* Hbf = (unsigned short*)(ws + OFF_HBF);
  float* DTBC         = (float*)(ws + OFF_DTBC);
  float* Yb           = (float*)(ws + OFF_Y);
  unsigned short* Xn  = (unsigned short*)(ws + OFF_XNG);
  float* Hc           = (float*)(ws + OFF_XNG);          // 8 MB (scan lifetime only)
  float* Pc           = (float*)(ws + OFF_XNG + 8388608);// 8 MB
  unsigned short* Gb  = (unsigned short*)(ws + OFF_XNG);
  unsigned short* WinT   = (unsigned short*)(ws + OFF_WINT);
  unsigned short* WdtBCT = (unsigned short*)(ws + OFF_WDTBCT);
  unsigned short* WoutT  = (unsigned short*)(ws + OFF_WOUTT);
  float* bias2        = (float*)(ws + OFF_BIAS2);

  pos_kernel<<<4096, 256, 0, stream>>>(x_in, pos, X);

  for (int i = 0; i < 2; i++) {
    // ---- weight prep (bf16, transposed to [N][K]) ----
    tcvt_kernel<<<dim3(2048 / 64, 1024 / 64), 256, 0, stream>>>(
        Win + (size_t)i * D_MODEL * DIN, WinT, 1024, 2048);
    // zero only the pad rows 2080..2175 of WdtBCT
    zero_kernel<<<(96 * 2048 * 2 / 16) / 256, 256, 0, stream>>>(
        (uint4*)(WdtBCT + (size_t)2080 * 2048));
    tcvt_kernel<<<dim3(2048 / 64, 2048 / 64), 256, 0, stream>>>(
        Wdt + (size_t)i * DIN * DIN, WdtBCT, 2048, 2048);
    bcfill_kernel<<<(32 * 2048) / 256, 256, 0, stream>>>(
        WB + (size_t)i * DIN * NSTATE, WC + (size_t)i * DIN * NSTATE, WdtBCT);
    biasfill_kernel<<<9, 256, 0, stream>>>(b_dt + (size_t)i * DIN, bias2);
    tcvt_kernel<<<dim3(1024 / 64, 2048 / 64), 256, 0, stream>>>(
        Wout + (size_t)i * DIN * D_MODEL, WoutT, 2048, 1024);

    // ---- layer compute ----
    ln_kernel<<<4096, 256, 0, stream>>>(X, norm_w + i * D_MODEL, norm_b + i * D_MODEL,
                                        Xn, nullptr);
    gemm_kernel<false, true><<<dim3(2048 / 128, 4096 / 128), 256, 0, stream>>>(
        Xn, WinT, b_in + (size_t)i * DIN, nullptr, Hb, Hbf, NROWS, DIN, D_MODEL, 0);
    gemm_kernel<false, false><<<dim3(NCOL / 128, 4096 / 128), 256, 0, stream>>>(
        Hbf, WdtBCT, bias2, nullptr, DTBC, nullptr, NROWS, NCOL, DIN, DIN);
    scan1_kernel<<<dim3(DIN / 256, NBATCH, CCH), 256, 0, stream>>>(
        DTBC, Hb, A_log + (size_t)i * DIN * NSTATE, Hc, Pc);
    scomb_kernel<<<(NBATCH * DIN * NSTATE) / 256, 256, 0, stream>>>(Hc, Pc);
    scan2_kernel<<<dim3(DIN / 256, NBATCH, CCH), 256, 0, stream>>>(
        DTBC, Hb, A_log + (size_t)i * DIN * NSTATE, Hc, Yb);
    gate_kernel<<<(NBATCH * LSEQ * DIN / 4) / 256, 256, 0, stream>>>(
        Hb, Yb, conv_w + (size_t)i * 4 * DIN, conv_b + (size_t)i * DIN,
        Dsk + (size_t)i * DIN, Gb);
    gemm_kernel<true, false><<<dim3(1024 / 128, 4096 / 128), 256, 0, stream>>>(
        Gb, WoutT, b_out + (size_t)i * D_MODEL, X, X, nullptr, NROWS, D_MODEL, DIN, 0);
  }

  ln_kernel<<<4096, 256, 0, stream>>>(X, fnw, fnb, nullptr, (float*)d_out);
}